// Round 5
// baseline (126.040 us; speedup 1.0000x reference)
//
#include <hip/hip_runtime.h>

// Polyphase resample up=3 down=2, N=2097152, L=129 taps, start=(L-1)/2=64.
// out[3j+0] = 3 * sum_i x[21+2j-i] * h[1+3i]   (i in [0,43))
// out[3j+1] = 3 * sum_i x[22+2j-i] * h[0+3i]
// out[3j+2] = 3 * sum_i x[22+2j-i] * h[2+3i]
// (formula verified: R1-R4 passed, absmax 0.25)
//
// R5 = DIAGNOSTIC ROUND. Two missed predictions in a row; poly_kernel has
// been invisible in rocprof top-5 (< 42us fill floor) since R3. This round
// wraps the identical R4 body in an internal x8 repeat (reps 0..6 store to
// d_ws, rep 7 to d_out; LDS re-staged per rep so nothing can be hoisted).
// Purpose: (1) force poly into top-5 to capture its real counters,
// (2) (dur_R5 - dur_R4)/7 = true body time, discriminating
//     model A (body ~28us, latency-stalled) vs model B (body ~3-5us,
//     harness floor dominates dur_us).

#define N_SIG   2097152
#define L_FILT  129
#define NTAPS   43
#define G       2                            // 2 groups = 6 outputs/thread
#define BLK     256
#define GROUPS_PER_BLK (BLK * G)             // 512 groups -> 1536 outputs/block
#define TILE_Q  1072                         // logical words, covers q in [3,1069)
#define TILE_P  (TILE_Q + TILE_Q / 4)        // 1340: 1 pad word per 4 -> stride 5
#define REPS    8

// Window for a chunk of U taps starting at compile-time tap I0:
// wz[k] = w[D+k], D = 46-U-I0, size U+3. Padded addr of w[d]:
// p = Q + (Q>>2), Q = 4*tid + d; R = D&3 compile-time.
template <int U, int I0>
__device__ __forceinline__ void load_win(const float* __restrict__ xs,
                                         int tid, float (&wz)[U + 3]) {
    constexpr int D = 46 - U - I0;
    constexpr int R = D & 3;
    const int pb = 5 * tid + D + (D >> 2);
#pragma unroll
    for (int k = 0; k < U + 3; ++k)
        wz[k] = xs[pb + k + ((R + k) >> 2)];
}

template <int U, int I0>
__device__ __forceinline__ void fmas(const float* __restrict__ h,
                                     const float (&wz)[U + 3], float (&acc)[3 * G]) {
#pragma unroll
    for (int u = 0; u < U; ++u) {
        const float h0 = h[3 * (I0 + u) + 0];
        const float h1 = h[3 * (I0 + u) + 1];
        const float h2 = h[3 * (I0 + u) + 2];
#pragma unroll
        for (int g = 0; g < G; ++g) {
            const float xa = wz[U - 1 - u + 2 * g];
            const float xb = wz[U - u + 2 * g];
            acc[3 * g + 0] += xa * h1;
            acc[3 * g + 1] += xb * h0;
            acc[3 * g + 2] += xb * h2;
        }
    }
}

__global__ __launch_bounds__(BLK, 4) void poly_kernel(
    const float* __restrict__ x, const float* __restrict__ h,
    float* __restrict__ out, float* __restrict__ ws, int n_out, int reps)
{
    __shared__ float xs[TILE_P];

    const int tid = threadIdx.x;
    const int b   = blockIdx.x;
    const int tb  = 2 * GROUPS_PER_BLK * b - 24;

#pragma unroll 1
    for (int rep = 0; rep < reps; ++rep) {
        // Coalesced staging with zero-pad at edges. Word q at p = q + (q>>2).
        for (int q4 = tid; q4 < TILE_Q / 4; q4 += BLK) {
            const int gx = tb + 4 * q4;
            float4 v;
            if (gx >= 0 && gx + 3 < N_SIG) {
                v = *(const float4*)(x + gx);
            } else {
                v.x = (gx     >= 0 && gx     < N_SIG) ? x[gx]     : 0.0f;
                v.y = (gx + 1 >= 0 && gx + 1 < N_SIG) ? x[gx + 1] : 0.0f;
                v.z = (gx + 2 >= 0 && gx + 2 < N_SIG) ? x[gx + 2] : 0.0f;
                v.w = (gx + 3 >= 0 && gx + 3 < N_SIG) ? x[gx + 3] : 0.0f;
            }
            const int p = 5 * q4;
            xs[p + 0] = v.x; xs[p + 1] = v.y; xs[p + 2] = v.z; xs[p + 3] = v.w;
        }
        __syncthreads();

        float acc[3 * G];
#pragma unroll
        for (int k = 0; k < 3 * G; ++k) acc[k] = 0.0f;

        // Software-pipelined chunks (identical to R4).
        float w0[11], w1[11], wt[6];
        load_win<8, 0 >(xs, tid, w0);
        load_win<8, 8 >(xs, tid, w1);
        fmas<8, 0 >(h, w0, acc);
        load_win<8, 16>(xs, tid, w0);
        fmas<8, 8 >(h, w1, acc);
        load_win<8, 24>(xs, tid, w1);
        fmas<8, 16>(h, w0, acc);
        load_win<8, 32>(xs, tid, w0);
        fmas<8, 24>(h, w1, acc);
        load_win<3, 40>(xs, tid, wt);
        fmas<8, 32>(h, w0, acc);
        fmas<3, 40>(h, wt, acc);

        // reps 0..6 -> ws (keeps every rep's compute live); last rep -> out.
        float* __restrict__ o = (rep + 1 == reps) ? out : ws;
        const int ob = 3 * GROUPS_PER_BLK * b + 3 * G * tid;
#pragma unroll
        for (int k = 0; k < 3; ++k) {
            if (ob + 2 * k + 1 < n_out) {
                *(float2*)(o + ob + 2 * k) =
                    make_float2(3.0f * acc[2 * k], 3.0f * acc[2 * k + 1]);
            }
        }
        __syncthreads();   // WAR: all xs reads done before next rep re-stages
    }
}

extern "C" void kernel_launch(void* const* d_in, const int* in_sizes, int n_in,
                              void* d_out, int out_size, void* d_ws, size_t ws_size,
                              hipStream_t stream) {
    const float* x = (const float*)d_in[0];
    const float* h = (const float*)d_in[1];
    float* out = (float*)d_out;
    // Scratch target for non-final reps; fall back to d_out if ws too small.
    float* ws = (ws_size >= (size_t)out_size * sizeof(float))
                    ? (float*)d_ws : out;
    const int blocks = (out_size + 3 * GROUPS_PER_BLK - 1) / (3 * GROUPS_PER_BLK);
    poly_kernel<<<blocks, BLK, 0, stream>>>(x, h, out, ws, out_size, REPS);
}

// Round 6
// 73.392 us; speedup vs baseline: 1.7174x; 1.7174x over previous
//
#include <hip/hip_runtime.h>

// Polyphase resample up=3 down=2, N=2097152, L=129 taps, start=(L-1)/2=64.
// out[3j+0] = 3 * sum_i x[21+2j-i] * h[1+3i]   (i in [0,43))
// out[3j+1] = 3 * sum_i x[22+2j-i] * h[0+3i]
// out[3j+2] = 3 * sum_i x[22+2j-i] * h[2+3i]
// (formula verified: R1-R5 passed, absmax 0.25)
//
// R5 diagnostic: body ~9.3us/rep, ~68% issue-stall (per-SIMD), latency-bound;
// dur_us carries ~60us fixed harness overhead. R6: b128 windows (17 LDS reads
// vs 52), depth-2 pipeline (FMA time 2 chunks > ds latency), BLK=128 x 4096
// blocks, exact-grid epilogue (no guards), edge-checked staging only b=0/last.

#define N_SIG   2097152
#define L_FILT  129
#define G       2
#define BLK     128
#define GPB     (BLK * G)          // 256 groups/block
#define OPB     (3 * GPB)          // 768 outputs/block; 3145728/768 = 4096 exact
#define TILE_Q  560                // staged words; needed q in [4, 560)

// tb = 512b - 26. Word q holds x[tb+q]. Thread tid, chunk taps [I0, I0+8):
// window words [D, D+12), D = 40 - I0 (so 4*tid+D is 16B-aligned).
// xa(u,g) = wz[7-u+2g], xb(u,g) = wz[8-u+2g].
template <int I0>
__device__ __forceinline__ void load_win8(const float* __restrict__ xs, int tid,
                                          float (&wz)[12]) {
    const float4* p = (const float4*)(xs + 4 * tid + (40 - I0));
    const float4 a = p[0], b = p[1], c = p[2];
    wz[0] = a.x; wz[1]  = a.y; wz[2]  = a.z; wz[3]  = a.w;
    wz[4] = b.x; wz[5]  = b.y; wz[6]  = b.z; wz[7]  = b.w;
    wz[8] = c.x; wz[9]  = c.y; wz[10] = c.z; wz[11] = c.w;
}

template <int I0>
__device__ __forceinline__ void fma8(const float* __restrict__ h,
                                     const float (&wz)[12], float (&acc)[6]) {
#pragma unroll
    for (int u = 0; u < 8; ++u) {
        const float h0 = h[3 * (I0 + u) + 0];   // uniform const idx -> s_load
        const float h1 = h[3 * (I0 + u) + 1];
        const float h2 = h[3 * (I0 + u) + 2];
#pragma unroll
        for (int g = 0; g < 2; ++g) {
            const float xa = wz[7 - u + 2 * g];
            const float xb = wz[8 - u + 2 * g];
            acc[3 * g + 0] += xa * h1;
            acc[3 * g + 1] += xb * h0;
            acc[3 * g + 2] += xb * h2;
        }
    }
}

// Tail taps 40..42: window words [4, 12); xa = wt[3-u+2g], xb = wt[4-u+2g].
__device__ __forceinline__ void load_tail(const float* __restrict__ xs, int tid,
                                          float (&wt)[8]) {
    const float4* p = (const float4*)(xs + 4 * tid + 4);
    const float4 a = p[0], b = p[1];
    wt[0] = a.x; wt[1] = a.y; wt[2] = a.z; wt[3] = a.w;
    wt[4] = b.x; wt[5] = b.y; wt[6] = b.z; wt[7] = b.w;
}

__device__ __forceinline__ void fma_tail(const float* __restrict__ h,
                                         const float (&wt)[8], float (&acc)[6]) {
#pragma unroll
    for (int u = 0; u < 3; ++u) {
        const float h0 = h[3 * (40 + u) + 0];
        const float h1 = h[3 * (40 + u) + 1];
        const float h2 = h[3 * (40 + u) + 2];
#pragma unroll
        for (int g = 0; g < 2; ++g) {
            const float xa = wt[3 - u + 2 * g];
            const float xb = wt[4 - u + 2 * g];
            acc[3 * g + 0] += xa * h1;
            acc[3 * g + 1] += xb * h0;
            acc[3 * g + 2] += xb * h2;
        }
    }
}

__global__ __launch_bounds__(BLK, 6) void poly_kernel(
    const float* __restrict__ x, const float* __restrict__ h,
    float* __restrict__ out, int nblocks)
{
    __shared__ alignas(16) float xs[TILE_Q];

    const int tid = threadIdx.x;
    const int b   = blockIdx.x;
    const int tb  = 512 * b - 26;

    if (b != 0 && b != nblocks - 1) {
        // Interior fast path. Global addr tb+4q4 is 8B-aligned (tb%4 == 2):
        // two float2 loads per 16B LDS store, no bounds checks.
        {
            const float* g0 = x + (tb + 4 * tid);
            const float2 lo = *(const float2*)(g0);
            const float2 hi = *(const float2*)(g0 + 2);
            *(float4*)(xs + 4 * tid) = make_float4(lo.x, lo.y, hi.x, hi.y);
        }
        if (tid < TILE_Q / 4 - BLK) {   // 12 threads stage the tile tail
            const float* g0 = x + (tb + 4 * (BLK + tid));
            const float2 lo = *(const float2*)(g0);
            const float2 hi = *(const float2*)(g0 + 2);
            *(float4*)(xs + 4 * (BLK + tid)) = make_float4(lo.x, lo.y, hi.x, hi.y);
        }
    } else {
        // Edge blocks: element-checked, zero-padded.
        for (int q4 = tid; q4 < TILE_Q / 4; q4 += BLK) {
            const int gx = tb + 4 * q4;
            float4 v;
            v.x = (gx     >= 0 && gx     < N_SIG) ? x[gx]     : 0.0f;
            v.y = (gx + 1 >= 0 && gx + 1 < N_SIG) ? x[gx + 1] : 0.0f;
            v.z = (gx + 2 >= 0 && gx + 2 < N_SIG) ? x[gx + 2] : 0.0f;
            v.w = (gx + 3 >= 0 && gx + 3 < N_SIG) ? x[gx + 3] : 0.0f;
            *(float4*)(xs + 4 * q4) = v;
        }
    }
    __syncthreads();

    float acc[6] = {0.f, 0.f, 0.f, 0.f, 0.f, 0.f};

    // Depth-2 pipeline: two chunk windows always in flight ahead of the FMAs.
    float wA[12], wB[12], wC[12], wT[8];
    load_win8<0>(xs, tid, wA);
    load_win8<8>(xs, tid, wB);
    load_win8<16>(xs, tid, wC);
    fma8<0>(h, wA, acc);
    load_win8<24>(xs, tid, wA);
    fma8<8>(h, wB, acc);
    load_win8<32>(xs, tid, wB);
    fma8<16>(h, wC, acc);
    load_tail(xs, tid, wT);
    fma8<24>(h, wA, acc);
    fma8<32>(h, wB, acc);
    fma_tail(h, wT, acc);

    // Exact grid (4096 * 768 == out_size): unguarded stores; fold gain 3.
    const int ob = OPB * b + 6 * tid;
    *(float2*)(out + ob + 0) = make_float2(3.0f * acc[0], 3.0f * acc[1]);
    *(float2*)(out + ob + 2) = make_float2(3.0f * acc[2], 3.0f * acc[3]);
    *(float2*)(out + ob + 4) = make_float2(3.0f * acc[4], 3.0f * acc[5]);
}

extern "C" void kernel_launch(void* const* d_in, const int* in_sizes, int n_in,
                              void* d_out, int out_size, void* d_ws, size_t ws_size,
                              hipStream_t stream) {
    const float* x = (const float*)d_in[0];
    const float* h = (const float*)d_in[1];
    float* out = (float*)d_out;
    const int blocks = (out_size + OPB - 1) / OPB;   // 4096, exact
    poly_kernel<<<blocks, BLK, 0, stream>>>(x, h, out, blocks);
}

// Round 8
// 71.288 us; speedup vs baseline: 1.7680x; 1.0295x over previous
//
#include <hip/hip_runtime.h>

// Polyphase resample up=3 down=2, N=2097152, L=129 taps, start=(L-1)/2=64.
// out[3j+0] = 3 * sum_i x[21+2j-i] * h[1+3i]   (i in [0,43))
// out[3j+1] = 3 * sum_i x[22+2j-i] * h[0+3i]
// out[3j+2] = 3 * sum_i x[22+2j-i] * h[2+3i]
// (formula verified: R1-R6 passed, absmax 0.25)
//
// R6 post-mortem: single-shot kernel ~21us = 7.5us issue (R5 steady-state)
// + ~14us cold-start latency under the harness's 268MB dirty-poison L2/L3.
// R7/R8 attacks the cold component: NO LDS / NO barrier (each thread direct-
// loads its 52-word register window via 13 aligned dwordx4 -> no wave waits
// on another wave's miss), and non-temporal output stores (don't allocate
// into the dirty L3 -> no forced write-back on the store path).
// R8 = R7 with the nontemporal-store type fixed (clang ext_vector, not
// HIP_vector_type, which __builtin_nontemporal_store rejects).

#define N_SIG   2097152
#define G       2
#define BLK     256
#define GPB     (BLK * G)      // 512 groups/block
#define OPB     (3 * GPB)      // 1536 outputs/block; 3145728/1536 = 2048 exact
#define NW      52             // register window: words d in [2,54)

typedef float v2f __attribute__((ext_vector_type(2)));

// Thread (b,t): w[d-2] = x[tb + 4t + d], tb = 1024b - 26.
// Tap i, group g (j = 512b + 2t + g):
//   xa = x[21+2j-i] = word 47+2g-i -> w[45+2g-i]
//   xb = x[22+2j-i] = word 48+2g-i -> w[46+2g-i]
// Needed w indices: taps 0..42, g 0..1 -> [3, 48] (all in range).

template <int I0>
__device__ __forceinline__ void fma8(const float* __restrict__ h,
                                     const float (&w)[NW], float (&acc)[6]) {
#pragma unroll
    for (int u = 0; u < 8; ++u) {
        const float h0 = h[3 * (I0 + u) + 0];   // uniform const idx -> s_load
        const float h1 = h[3 * (I0 + u) + 1];
        const float h2 = h[3 * (I0 + u) + 2];
#pragma unroll
        for (int g = 0; g < 2; ++g) {
            const float xa = w[45 - (I0 + u) + 2 * g];
            const float xb = w[46 - (I0 + u) + 2 * g];
            acc[3 * g + 0] += xa * h1;
            acc[3 * g + 1] += xb * h0;
            acc[3 * g + 2] += xb * h2;
        }
    }
}

__global__ __launch_bounds__(BLK, 4) void poly_kernel(
    const float* __restrict__ x, const float* __restrict__ h,
    float* __restrict__ out, int nblocks)
{
    const int tid = threadIdx.x;
    const int b   = blockIdx.x;

    // Window base (word d=2): 1024b + 4t - 24; 16B-aligned.
    const long base = (long)1024 * b + 4 * tid - 24;

    float w[NW];
    if (b != 0 && b != nblocks - 1) {
        // Interior: 13 aligned float4 loads, no bounds checks.
        // (b in [1,2046]: min addr 1000, max addr 2096151 < N_SIG.)
        // Reverse issue order: chunk I0=0 consumes k=9..12 first -> those
        // are the oldest outstanding loads -> partial vmcnt waits.
        const float4* p = (const float4*)(x + base);
#pragma unroll
        for (int k = 12; k >= 0; --k) {
            const float4 v = p[k];
            w[4 * k + 0] = v.x; w[4 * k + 1] = v.y;
            w[4 * k + 2] = v.z; w[4 * k + 3] = v.w;
        }
    } else {
        // Edge blocks (2 of 2048): element-guarded, zero-padded.
#pragma unroll
        for (int k = 0; k < NW; ++k) {
            const long gi = base + k;
            w[k] = (gi >= 0 && gi < N_SIG) ? x[gi] : 0.0f;
        }
    }

    float acc[6] = {0.f, 0.f, 0.f, 0.f, 0.f, 0.f};
    fma8<0 >(h, w, acc);
    fma8<8 >(h, w, acc);
    fma8<16>(h, w, acc);
    fma8<24>(h, w, acc);
    fma8<32>(h, w, acc);
    // Tail taps 40..42.
#pragma unroll
    for (int u = 0; u < 3; ++u) {
        const float h0 = h[3 * (40 + u) + 0];
        const float h1 = h[3 * (40 + u) + 1];
        const float h2 = h[3 * (40 + u) + 2];
#pragma unroll
        for (int g = 0; g < 2; ++g) {
            const float xa = w[5 - u + 2 * g];
            const float xb = w[6 - u + 2 * g];
            acc[3 * g + 0] += xa * h1;
            acc[3 * g + 1] += xb * h0;
            acc[3 * g + 2] += xb * h2;
        }
    }

    // Exact grid: unguarded nt stores (ob even -> 8B-aligned); fold gain 3.
    const int ob = OPB * b + 6 * tid;
    v2f s0; s0.x = 3.0f * acc[0]; s0.y = 3.0f * acc[1];
    v2f s1; s1.x = 3.0f * acc[2]; s1.y = 3.0f * acc[3];
    v2f s2; s2.x = 3.0f * acc[4]; s2.y = 3.0f * acc[5];
    __builtin_nontemporal_store(s0, (v2f*)(out + ob + 0));
    __builtin_nontemporal_store(s1, (v2f*)(out + ob + 2));
    __builtin_nontemporal_store(s2, (v2f*)(out + ob + 4));
}

extern "C" void kernel_launch(void* const* d_in, const int* in_sizes, int n_in,
                              void* d_out, int out_size, void* d_ws, size_t ws_size,
                              hipStream_t stream) {
    const float* x = (const float*)d_in[0];
    const float* h = (const float*)d_in[1];
    float* out = (float*)d_out;
    const int blocks = (out_size + OPB - 1) / OPB;   // 2048, exact
    poly_kernel<<<blocks, BLK, 0, stream>>>(x, h, out, blocks);
}